// Round 1
// 1117.670 us; speedup vs baseline: 1.2945x; 1.2945x over previous
//
#include <hip/hip_runtime.h>

#define C_DIM 768
#define K_DIM 2304
#define BZ 16
#define NK (K_DIM / 32)   // 72 K-steps, divisible by 3

typedef short bf16x8 __attribute__((ext_vector_type(8)));
typedef float f32x4 __attribute__((ext_vector_type(4)));

#define GLOBAL_AS __attribute__((address_space(1)))
#define LDS_AS __attribute__((address_space(3)))

// Async global->LDS, 16B per lane. LDS dest is wave-uniform base + lane*16.
__device__ __forceinline__ void async_copy16(const void* g, void* l) {
    __builtin_amdgcn_global_load_lds(
        (GLOBAL_AS void*)(unsigned long long)(uintptr_t)g,
        (LDS_AS void*)(unsigned int)(uintptr_t)l,
        16, 0, 0);
}

__device__ __forceinline__ unsigned short f_to_bf16(float f) {
    union { float f; unsigned int i; } v; v.f = f;
    unsigned int r = v.i + 0x7FFFu + ((v.i >> 16) & 1u);  // RNE
    return (unsigned short)(r >> 16);
}

// Implicit-GEMM conv: out[g, n] = act( sum_k A[g,k] * Bt[n,k] + bias[n] )
// Row g -> sample b = g >> p_shift, position p = g & ((1<<p_shift)-1).
// A window = Abase + b*a_samp_stride + (p*sa)*C_DIM, 3*C_DIM contiguous bf16
// (padded layout: data row p at padded row p+1; pad rows zero).
// MODE 0: conv1 -> gelu -> bf16 to out_bf. MODE 1: conv2 -> fp32 + bf16 next-x.
// MODE 2: conv2 last level -> fp32/new_len only.
//
// K-loop: 3-buffer software pipeline. Step ks reads buf[ks%3]; stage for step
// ks+2 is issued at the TOP of step ks (2 iterations of latency hiding).
// End-of-step sync is lgkmcnt(0) (reads drained before buffer reuse) +
// COUNTED vmcnt(4) (only step ks+1's 4 loads may stay in flight — never a
// full drain in the main loop) + raw s_barrier. __syncthreads is NOT used in
// the loop: it would force vmcnt(0) and expose full load latency per step.
template<int MODE>
__global__ __launch_bounds__(256)
void gemm_conv(const unsigned short* __restrict__ Abase,
               const unsigned short* __restrict__ Bt,
               const float* __restrict__ bias,
               const int* __restrict__ lens,
               unsigned short* __restrict__ out_bf,
               float* __restrict__ out_f,
               int M, int p_shift, int a_samp_stride, int sa,
               int o_samp_stride, int len_shift)
{
    // 3 double... triple-buffered [128][32] short tiles (16 KB each set, 48 KB).
    __shared__ __align__(16) short lsA[3][128 * 32];
    __shared__ __align__(16) short lsB[3][128 * 32];

    const int t = threadIdx.x;
    const int lane = t & 63;
    const int wave = t >> 6;

    // T1: bijective XCD-chunked remap (m204 formula). wgid = tile_m*6 + tile_n
    // (n fastest), so one XCD's contiguous chunk covers all 6 n-tiles of each
    // of its m-tiles -> the A panel is fetched into ONE XCD's L2 and reused 6x,
    // and conv2 reads conv1's output chunk from the same XCD's L2.
    const int nwg = gridDim.x;
    const int orig = blockIdx.x;
    const int qc = nwg >> 3, rc = nwg & 7;
    const int xcd = orig & 7;
    const int wgid = (xcd < rc ? xcd * (qc + 1)
                               : rc * (qc + 1) + (xcd - rc) * qc) + (orig >> 3);
    const int tile_m = wgid / 6;
    const int tile_n = wgid - tile_m * 6;

    const int Pmask = (1 << p_shift) - 1;

    // Staging: 512 16B-chunks per tile per K-step; chunk cix = it*256 + t,
    // r = cix>>2, q4 = cix&3  ->  LDS offset cix*16B == r*64B + q4*16B.
    const unsigned short* pA[2];
    const unsigned short* pB[2];
    int dofs[2];
#pragma unroll
    for (int it = 0; it < 2; ++it) {
        int cix = it * 256 + t;
        int r = cix >> 2, q4 = cix & 3;
        int g = tile_m * 128 + r; if (g > M - 1) g = M - 1;   // clamp: dup reads safe
        int b = g >> p_shift, p = g & Pmask;
        pA[it] = Abase + (size_t)b * a_samp_stride + (size_t)(p * sa) * C_DIM + q4 * 8;
        pB[it] = Bt + (size_t)(tile_n * 128 + r) * K_DIM + q4 * 8;
        dofs[it] = (it * 256 + wave * 64) * 8;   // wave-uniform; lane*16B added by HW
    }

    const f32x4 fzero = {0.0f, 0.0f, 0.0f, 0.0f};
    f32x4 acc[4][4];
#pragma unroll
    for (int i = 0; i < 4; ++i)
#pragma unroll
        for (int j = 0; j < 4; ++j) acc[i][j] = fzero;

    const int wm = (wave >> 1) * 64, wn = (wave & 1) * 64;
    const int lrow = lane & 15;
    const int lko = (lane >> 4) * 8;

    auto stage = [&](int s, int bi) {
        const int koff = s * 32;
#pragma unroll
        for (int it = 0; it < 2; ++it) {
            async_copy16(pA[it] + koff, &lsA[bi][dofs[it]]);
            async_copy16(pB[it] + koff, &lsB[bi][dofs[it]]);
        }
    };

    auto kstep = [&](int ks, const short* LA, const short* LB, int sbuf) {
        if (ks + 2 < NK) stage(ks + 2, sbuf);       // prefetch 2 steps ahead
        bf16x8 af[4], bfv[4];
#pragma unroll
        for (int i = 0; i < 4; ++i) {
            af[i]  = *(const bf16x8*)&LA[(wm + i * 16 + lrow) * 32 + lko];
            bfv[i] = *(const bf16x8*)&LB[(wn + i * 16 + lrow) * 32 + lko];
        }
#pragma unroll
        for (int i = 0; i < 4; ++i)
#pragma unroll
            for (int j = 0; j < 4; ++j)
                acc[i][j] = __builtin_amdgcn_mfma_f32_16x16x32_bf16(af[i], bfv[j], acc[i][j], 0, 0, 0);
        if (ks + 1 < NK) {
            // Drain this wave's LDS reads BEFORE the barrier: the buffer read
            // this step is overwritten by next step's stage (anti-dep).
            asm volatile("s_waitcnt lgkmcnt(0)" ::: "memory");
            // Counted vmcnt: require step ks+1's chunks landed (oldest), allow
            // the 4 just-issued (step ks+2) to stay in flight.
            if (ks + 2 < NK) asm volatile("s_waitcnt vmcnt(4)" ::: "memory");
            else             asm volatile("s_waitcnt vmcnt(0)" ::: "memory");
            __builtin_amdgcn_s_barrier();
            asm volatile("" ::: "memory");          // no mem-op motion across
        }
    };

    // Pipeline prologue: steps 0 and 1 in flight; wait step 0, leave step 1.
    stage(0, 0);
    stage(1, 1);
    asm volatile("s_waitcnt vmcnt(4)" ::: "memory");
    __builtin_amdgcn_s_barrier();
    asm volatile("" ::: "memory");

    // Unrolled x3 so each step's LDS base is a compile-time constant.
    for (int ks = 0; ks < NK; ks += 3) {
        kstep(ks,     lsA[0], lsB[0], 2);
        kstep(ks + 1, lsA[1], lsB[1], 0);
        kstep(ks + 2, lsA[2], lsB[2], 1);
    }

    // Pad-row zeroing folded into the epilogue.
    if (MODE == 0 && tile_m == 0) {
        for (int s = t; s < BZ * 128; s += 256) {
            int b = s >> 7, c = tile_n * 128 + (s & 127);
            out_bf[(size_t)b * o_samp_stride + c] = 0;        // hbuf pad row 0
        }
    }
    if (MODE == 1 && tile_m == 0) {
        const int P_out = M >> 4;                              // M = BZ * P_out
        for (int s = t; s < 2 * BZ * 128; s += 256) {
            int rr = s >> 11;                                  // 0 or 1
            int b = (s >> 7) & 15, c = tile_n * 128 + (s & 127);
            size_t row = rr ? (size_t)(P_out + 1) : 0;
            out_bf[(size_t)b * o_samp_stride + row * C_DIM + c] = 0;
        }
    }

    // Epilogue. C/D layout: col = lane&15, row = (lane>>4)*4 + reg.
    int ncol[4]; float bv[4];
#pragma unroll
    for (int j = 0; j < 4; ++j) {
        ncol[j] = tile_n * 128 + wn + j * 16 + lrow;
        bv[j] = bias[ncol[j]];
    }
    const int rowbase = tile_m * 128 + wm + (lane >> 4) * 4;
#pragma unroll
    for (int i = 0; i < 4; ++i) {
#pragma unroll
        for (int rr = 0; rr < 4; ++rr) {
            int g = rowbase + i * 16 + rr;
            if (g >= M) continue;
            int b = g >> p_shift, p = g & Pmask;
            int lim = (lens[b] + (1 << len_shift) - 1) >> len_shift;  // ceil(len/2^s)
            bool valid = p < lim;
#pragma unroll
            for (int j = 0; j < 4; ++j) {
                float v = acc[i][j][rr] + bv[j];
                if (MODE == 0) {
                    float gl = 0.5f * v * (1.0f + erff(v * 0.70710678118654752f));
                    if (!valid) gl = 0.0f;
                    out_bf[(size_t)b * o_samp_stride + (size_t)(p + 1) * C_DIM + ncol[j]] = f_to_bf16(gl);
                } else {
                    if (!valid) v = 0.0f;
                    if (MODE == 2) v *= (1.0f / (float)lim);  // pooled = y / new_len (==1)
                    out_f[(size_t)g * C_DIM + ncol[j]] = v;
                    if (MODE == 1)
                        out_bf[(size_t)b * o_samp_stride + (size_t)(p + 1) * C_DIM + ncol[j]] = f_to_bf16(v);
                }
            }
        }
    }
}

// Bt[n][kk*C+i] = w[n][i][kk], bf16 — GEMM-B in [N, K] so staging matches A's path.
__global__ void prep_weights(const float* __restrict__ w1, const float* __restrict__ w2,
                             unsigned short* __restrict__ Bt1, unsigned short* __restrict__ Bt2) {
    int idx = blockIdx.x * 256 + threadIdx.x;
    if (idx >= C_DIM * K_DIM) return;
    int n = idx / K_DIM, rem = idx - n * K_DIM;
    int kk = rem / C_DIM, i = rem - kk * C_DIM;
    int widx = (n * C_DIM + i) * 3 + kk;
    Bt1[idx] = f_to_bf16(w1[widx]);
    Bt2[idx] = f_to_bf16(w2[widx]);
}

// x0 padded buffer [BZ][2050][C] bf16: pad rows + beyond-length rows zeroed.
__global__ void prep_x0(const float* __restrict__ in, const int* __restrict__ lens,
                        unsigned short* __restrict__ xbuf) {
    int idx = blockIdx.x * 256 + threadIdx.x;
    const int tot = BZ * 2050 * (C_DIM / 4);
    if (idx >= tot) return;
    int c4 = idx % (C_DIM / 4);
    int rest = idx / (C_DIM / 4);
    int r = rest % 2050, b = rest / 2050;
    int p = r - 1;
    ushort4 v = {0, 0, 0, 0};
    if (p >= 0 && p < 2048 && p < lens[b]) {
        const float4 f = *(const float4*)(in + ((size_t)(b * 2048 + p)) * C_DIM + c4 * 4);
        v.x = f_to_bf16(f.x); v.y = f_to_bf16(f.y); v.z = f_to_bf16(f.z); v.w = f_to_bf16(f.w);
    }
    ((ushort4*)xbuf)[idx] = v;
}

// All 11 level masks, straight from lengths. Level-10 mask degenerates to 1.0.
__global__ void write_masks(const int* __restrict__ lens, float* __restrict__ out) {
    int l = blockIdx.y;
    int Pl = 1024 >> l;
    int idx = blockIdx.x * 256 + threadIdx.x;
    if (idx >= BZ * Pl) return;
    int b = idx / Pl, q = idx - b * Pl;
    size_t off = (size_t)BZ * C_DIM * (2048 - (1024 >> l)) + (size_t)BZ * (2048 - (2048 >> l));
    int nl = (lens[b] + (1 << (l + 1)) - 1) >> (l + 1);
    out[off + idx] = (q < nl) ? 1.0f : 0.0f;
}

extern "C" void kernel_launch(void* const* d_in, const int* in_sizes, int n_in,
                              void* d_out, int out_size, void* d_ws, size_t ws_size,
                              hipStream_t stream) {
    const float* seq = (const float*)d_in[0];
    const int* lens = (const int*)d_in[1];
    const float* w1 = (const float*)d_in[2];
    const float* b1 = (const float*)d_in[3];
    const float* w2 = (const float*)d_in[4];
    const float* b2 = (const float*)d_in[5];
    float* out = (float*)d_out;
    char* ws = (char*)d_ws;

    // ws layout (bytes): xbuf 0..50.4MB, hbuf @52MiB, Bt1 @104MiB, Bt2 @108MiB
    unsigned short* xbuf = (unsigned short*)(ws);
    unsigned short* hbuf = (unsigned short*)(ws + (size_t)(52u << 20));
    unsigned short* Bt1  = (unsigned short*)(ws + (size_t)(104u << 20));
    unsigned short* Bt2  = (unsigned short*)(ws + (size_t)(108u << 20));

    prep_weights<<<(C_DIM * K_DIM + 255) / 256, 256, 0, stream>>>(w1, w2, Bt1, Bt2);
    {
        int tot = BZ * 2050 * (C_DIM / 4);
        prep_x0<<<(tot + 255) / 256, 256, 0, stream>>>(seq, lens, xbuf);
    }
    write_masks<<<dim3(64, 11), 256, 0, stream>>>(lens, out);

    size_t y_off = 0;
    for (int l = 0; l < 11; ++l) {
        int P_in = 2048 >> l, P_out = P_in >> 1;
        int M1 = BZ * P_in, M2 = BZ * P_out;
        int sh_in = __builtin_ctz((unsigned)P_in), sh_out = __builtin_ctz((unsigned)P_out);
        int a_str = (P_in + 2) * C_DIM;   // padded sample stride of this level's x / h
        int x_str = (P_out + 2) * C_DIM;  // padded sample stride of next level's x
        int g1 = 6 * ((M1 + 127) / 128), g2 = 6 * ((M2 + 127) / 128);

        // conv1 + GELU + mask -> hbuf (padded, bf16); also zeroes hbuf pad row 0
        gemm_conv<0><<<g1, 256, 0, stream>>>(xbuf, Bt1, b1, lens, hbuf, nullptr,
                                             M1, sh_in, a_str, 1, a_str, l);
        // conv2 + mask -> d_out fp32 chunk (+ bf16 next-level x incl. pad rows)
        if (l < 10)
            gemm_conv<1><<<g2, 256, 0, stream>>>(hbuf, Bt2, b2, lens, xbuf, out + y_off,
                                                 M2, sh_out, a_str, 2, x_str, l + 1);
        else
            gemm_conv<2><<<g2, 256, 0, stream>>>(hbuf, Bt2, b2, lens, xbuf, out + y_off,
                                                 M2, sh_out, a_str, 2, x_str, l + 1);
        y_off += (size_t)M2 * C_DIM + (size_t)M2;  // y chunk then mask chunk
    }
}

// Round 2
// 1084.443 us; speedup vs baseline: 1.3341x; 1.0306x over previous
//
#include <hip/hip_runtime.h>

#define C_DIM 768
#define K_DIM 2304
#define BZ 16
#define NK (K_DIM / 32)   // 72 K-steps, divisible by 3

typedef short bf16x8 __attribute__((ext_vector_type(8)));
typedef float f32x4 __attribute__((ext_vector_type(4)));

#define GLOBAL_AS __attribute__((address_space(1)))
#define LDS_AS __attribute__((address_space(3)))

// Async global->LDS, 16B per lane. LDS dest is wave-uniform base + lane*16.
__device__ __forceinline__ void async_copy16(const void* g, void* l) {
    __builtin_amdgcn_global_load_lds(
        (GLOBAL_AS void*)(unsigned long long)(uintptr_t)g,
        (LDS_AS void*)(unsigned int)(uintptr_t)l,
        16, 0, 0);
}

__device__ __forceinline__ unsigned short f_to_bf16(float f) {
    union { float f; unsigned int i; } v; v.f = f;
    unsigned int r = v.i + 0x7FFFu + ((v.i >> 16) & 1u);  // RNE
    return (unsigned short)(r >> 16);
}

// Implicit-GEMM conv: out[g, n] = act( sum_k A[g,k] * Bt[n,k] + bias[n] )
// Row g -> sample b = g >> p_shift, position p = g & ((1<<p_shift)-1).
// A window = Abase + b*a_samp_stride + (p*sa)*C_DIM, 3*C_DIM contiguous bf16
// (padded layout: data row p at padded row p+1; pad rows zero).
// MODE 0: conv1 -> gelu -> bf16 to out_bf. MODE 1: conv2 -> fp32 + bf16 next-x.
// MODE 2: conv2 last level -> fp32/new_len only.
//
// K-loop: 3-buffer software pipeline, counted vmcnt (never 0 mid-loop).
//
// T2 LDS swizzle: tiles are [128 rows][4 x 16B chunks]. Linear layout puts
// bank-slot = (row&1)*4 + q -> 16 rows/2 slots = 8-way conflict on every
// ds_read_b128. Swizzle: LDS position (r, q) holds global chunk q^((r>>1)&3)
// (involution). Source-permuted at setup (global_load_lds dest must stay
// linear, rule: both-sides-or-neither); read applies the same XOR, which is
// a per-thread CONSTANT: (lane>>4) ^ ((lrow>>1)&3). Rows 0..7 then cover all
// 8 bank-slots bijectively; rows 8..15 repeat = 2-way = free.
template<int MODE>
__global__ __launch_bounds__(256)
void gemm_conv(const unsigned short* __restrict__ Abase,
               const unsigned short* __restrict__ Bt,
               const float* __restrict__ bias,
               const int* __restrict__ lens,
               unsigned short* __restrict__ out_bf,
               float* __restrict__ out_f,
               int M, int p_shift, int a_samp_stride, int sa,
               int o_samp_stride, int len_shift)
{
    // Triple-buffered [128][32] short tiles (16 KB per set, 48 KB total).
    __shared__ __align__(16) short lsA[3][128 * 32];
    __shared__ __align__(16) short lsB[3][128 * 32];

    const int t = threadIdx.x;
    const int lane = t & 63;
    const int wave = t >> 6;

    // T1: bijective XCD-chunked remap (m204 formula). wgid = tile_m*6 + tile_n
    // (n fastest), so one XCD's contiguous chunk covers all 6 n-tiles of each
    // of its m-tiles -> the A panel is fetched into ONE XCD's L2 and reused 6x,
    // and conv2 reads conv1's output chunk from the same XCD's L2.
    const int nwg = gridDim.x;
    const int orig = blockIdx.x;
    const int qc = nwg >> 3, rc = nwg & 7;
    const int xcd = orig & 7;
    const int wgid = (xcd < rc ? xcd * (qc + 1)
                               : rc * (qc + 1) + (xcd - rc) * qc) + (orig >> 3);
    const int tile_m = wgid / 6;
    const int tile_n = wgid - tile_m * 6;

    const int Pmask = (1 << p_shift) - 1;

    // Staging: 512 16B-chunks per tile per K-step; chunk cix = it*256 + t,
    // r = cix>>2, q_pos = cix&3 -> LDS offset cix*16B (linear). The global
    // source chunk is the swizzle-inverse: q_dat = q_pos ^ ((r>>1)&3).
    const unsigned short* pA[2];
    const unsigned short* pB[2];
    int dofs[2];
#pragma unroll
    for (int it = 0; it < 2; ++it) {
        int cix = it * 256 + t;
        int r = cix >> 2, q4 = cix & 3;
        int qd = q4 ^ ((r >> 1) & 3);                         // T2 source permute
        int g = tile_m * 128 + r; if (g > M - 1) g = M - 1;   // clamp: dup reads safe
        int b = g >> p_shift, p = g & Pmask;
        pA[it] = Abase + (size_t)b * a_samp_stride + (size_t)(p * sa) * C_DIM + qd * 8;
        pB[it] = Bt + (size_t)(tile_n * 128 + r) * K_DIM + qd * 8;
        dofs[it] = (it * 256 + wave * 64) * 8;   // wave-uniform; lane*16B added by HW
    }

    const f32x4 fzero = {0.0f, 0.0f, 0.0f, 0.0f};
    f32x4 acc[4][4];
#pragma unroll
    for (int i = 0; i < 4; ++i)
#pragma unroll
        for (int j = 0; j < 4; ++j) acc[i][j] = fzero;

    const int wm = (wave >> 1) * 64, wn = (wave & 1) * 64;
    const int lrow = lane & 15;
    // T2 read swizzle folded into the per-thread chunk offset: (row>>1)&3 ==
    // (lrow>>1)&3 because wm and i*16 don't touch row bits 1..2.
    const int lko = (((lane >> 4) ^ ((lrow >> 1) & 3))) * 8;

    auto stage = [&](int s, int bi) {
        const int koff = s * 32;
#pragma unroll
        for (int it = 0; it < 2; ++it) {
            async_copy16(pA[it] + koff, &lsA[bi][dofs[it]]);
            async_copy16(pB[it] + koff, &lsB[bi][dofs[it]]);
        }
    };

    auto kstep = [&](int ks, const short* LA, const short* LB, int sbuf) {
        if (ks + 2 < NK) stage(ks + 2, sbuf);       // prefetch 2 steps ahead
        bf16x8 af[4], bfv[4];
#pragma unroll
        for (int i = 0; i < 4; ++i) {
            af[i]  = *(const bf16x8*)&LA[(wm + i * 16 + lrow) * 32 + lko];
            bfv[i] = *(const bf16x8*)&LB[(wn + i * 16 + lrow) * 32 + lko];
        }
#pragma unroll
        for (int i = 0; i < 4; ++i)
#pragma unroll
            for (int j = 0; j < 4; ++j)
                acc[i][j] = __builtin_amdgcn_mfma_f32_16x16x32_bf16(af[i], bfv[j], acc[i][j], 0, 0, 0);
        if (ks + 1 < NK) {
            // Drain this wave's LDS reads BEFORE the barrier: the buffer read
            // this step is overwritten by next step's stage (anti-dep).
            asm volatile("s_waitcnt lgkmcnt(0)" ::: "memory");
            // Counted vmcnt: require step ks+1's chunks landed (oldest), allow
            // the 4 just-issued (step ks+2) to stay in flight.
            if (ks + 2 < NK) asm volatile("s_waitcnt vmcnt(4)" ::: "memory");
            else             asm volatile("s_waitcnt vmcnt(0)" ::: "memory");
            __builtin_amdgcn_s_barrier();
            asm volatile("" ::: "memory");          // no mem-op motion across
        }
    };

    // Pipeline prologue: steps 0 and 1 in flight; wait step 0, leave step 1.
    stage(0, 0);
    stage(1, 1);
    asm volatile("s_waitcnt vmcnt(4)" ::: "memory");
    __builtin_amdgcn_s_barrier();
    asm volatile("" ::: "memory");

    // Unrolled x3 so each step's LDS base is a compile-time constant.
    for (int ks = 0; ks < NK; ks += 3) {
        kstep(ks,     lsA[0], lsB[0], 2);
        kstep(ks + 1, lsA[1], lsB[1], 0);
        kstep(ks + 2, lsA[2], lsB[2], 1);
    }

    // Pad-row zeroing folded into the epilogue.
    if (MODE == 0 && tile_m == 0) {
        for (int s = t; s < BZ * 128; s += 256) {
            int b = s >> 7, c = tile_n * 128 + (s & 127);
            out_bf[(size_t)b * o_samp_stride + c] = 0;        // hbuf pad row 0
        }
    }
    if (MODE == 1 && tile_m == 0) {
        const int P_out = M >> 4;                              // M = BZ * P_out
        for (int s = t; s < 2 * BZ * 128; s += 256) {
            int rr = s >> 11;                                  // 0 or 1
            int b = (s >> 7) & 15, c = tile_n * 128 + (s & 127);
            size_t row = rr ? (size_t)(P_out + 1) : 0;
            out_bf[(size_t)b * o_samp_stride + row * C_DIM + c] = 0;
        }
    }

    // Epilogue. C/D layout: col = lane&15, row = (lane>>4)*4 + reg.
    int ncol[4]; float bv[4];
#pragma unroll
    for (int j = 0; j < 4; ++j) {
        ncol[j] = tile_n * 128 + wn + j * 16 + lrow;
        bv[j] = bias[ncol[j]];
    }
    const int rowbase = tile_m * 128 + wm + (lane >> 4) * 4;
#pragma unroll
    for (int i = 0; i < 4; ++i) {
#pragma unroll
        for (int rr = 0; rr < 4; ++rr) {
            int g = rowbase + i * 16 + rr;
            if (g >= M) continue;
            int b = g >> p_shift, p = g & Pmask;
            int lim = (lens[b] + (1 << len_shift) - 1) >> len_shift;  // ceil(len/2^s)
            bool valid = p < lim;
#pragma unroll
            for (int j = 0; j < 4; ++j) {
                float v = acc[i][j][rr] + bv[j];
                if (MODE == 0) {
                    float gl = 0.5f * v * (1.0f + erff(v * 0.70710678118654752f));
                    if (!valid) gl = 0.0f;
                    out_bf[(size_t)b * o_samp_stride + (size_t)(p + 1) * C_DIM + ncol[j]] = f_to_bf16(gl);
                } else {
                    if (!valid) v = 0.0f;
                    if (MODE == 2) v *= (1.0f / (float)lim);  // pooled = y / new_len (==1)
                    out_f[(size_t)g * C_DIM + ncol[j]] = v;
                    if (MODE == 1)
                        out_bf[(size_t)b * o_samp_stride + (size_t)(p + 1) * C_DIM + ncol[j]] = f_to_bf16(v);
                }
            }
        }
    }
}

// Bt[n][kk*C+i] = w[n][i][kk], bf16 — GEMM-B in [N, K] so staging matches A's path.
__global__ void prep_weights(const float* __restrict__ w1, const float* __restrict__ w2,
                             unsigned short* __restrict__ Bt1, unsigned short* __restrict__ Bt2) {
    int idx = blockIdx.x * 256 + threadIdx.x;
    if (idx >= C_DIM * K_DIM) return;
    int n = idx / K_DIM, rem = idx - n * K_DIM;
    int kk = rem / C_DIM, i = rem - kk * C_DIM;
    int widx = (n * C_DIM + i) * 3 + kk;
    Bt1[idx] = f_to_bf16(w1[widx]);
    Bt2[idx] = f_to_bf16(w2[widx]);
}

// x0 padded buffer [BZ][2050][C] bf16: pad rows + beyond-length rows zeroed.
__global__ void prep_x0(const float* __restrict__ in, const int* __restrict__ lens,
                        unsigned short* __restrict__ xbuf) {
    int idx = blockIdx.x * 256 + threadIdx.x;
    const int tot = BZ * 2050 * (C_DIM / 4);
    if (idx >= tot) return;
    int c4 = idx % (C_DIM / 4);
    int rest = idx / (C_DIM / 4);
    int r = rest % 2050, b = rest / 2050;
    int p = r - 1;
    ushort4 v = {0, 0, 0, 0};
    if (p >= 0 && p < 2048 && p < lens[b]) {
        const float4 f = *(const float4*)(in + ((size_t)(b * 2048 + p)) * C_DIM + c4 * 4);
        v.x = f_to_bf16(f.x); v.y = f_to_bf16(f.y); v.z = f_to_bf16(f.z); v.w = f_to_bf16(f.w);
    }
    ((ushort4*)xbuf)[idx] = v;
}

// All 11 level masks, straight from lengths. Level-10 mask degenerates to 1.0.
__global__ void write_masks(const int* __restrict__ lens, float* __restrict__ out) {
    int l = blockIdx.y;
    int Pl = 1024 >> l;
    int idx = blockIdx.x * 256 + threadIdx.x;
    if (idx >= BZ * Pl) return;
    int b = idx / Pl, q = idx - b * Pl;
    size_t off = (size_t)BZ * C_DIM * (2048 - (1024 >> l)) + (size_t)BZ * (2048 - (2048 >> l));
    int nl = (lens[b] + (1 << (l + 1)) - 1) >> (l + 1);
    out[off + idx] = (q < nl) ? 1.0f : 0.0f;
}

extern "C" void kernel_launch(void* const* d_in, const int* in_sizes, int n_in,
                              void* d_out, int out_size, void* d_ws, size_t ws_size,
                              hipStream_t stream) {
    const float* seq = (const float*)d_in[0];
    const int* lens = (const int*)d_in[1];
    const float* w1 = (const float*)d_in[2];
    const float* b1 = (const float*)d_in[3];
    const float* w2 = (const float*)d_in[4];
    const float* b2 = (const float*)d_in[5];
    float* out = (float*)d_out;
    char* ws = (char*)d_ws;

    // ws layout (bytes): xbuf 0..50.4MB, hbuf @52MiB, Bt1 @104MiB, Bt2 @108MiB
    unsigned short* xbuf = (unsigned short*)(ws);
    unsigned short* hbuf = (unsigned short*)(ws + (size_t)(52u << 20));
    unsigned short* Bt1  = (unsigned short*)(ws + (size_t)(104u << 20));
    unsigned short* Bt2  = (unsigned short*)(ws + (size_t)(108u << 20));

    prep_weights<<<(C_DIM * K_DIM + 255) / 256, 256, 0, stream>>>(w1, w2, Bt1, Bt2);
    {
        int tot = BZ * 2050 * (C_DIM / 4);
        prep_x0<<<(tot + 255) / 256, 256, 0, stream>>>(seq, lens, xbuf);
    }
    write_masks<<<dim3(64, 11), 256, 0, stream>>>(lens, out);

    size_t y_off = 0;
    for (int l = 0; l < 11; ++l) {
        int P_in = 2048 >> l, P_out = P_in >> 1;
        int M1 = BZ * P_in, M2 = BZ * P_out;
        int sh_in = __builtin_ctz((unsigned)P_in), sh_out = __builtin_ctz((unsigned)P_out);
        int a_str = (P_in + 2) * C_DIM;   // padded sample stride of this level's x / h
        int x_str = (P_out + 2) * C_DIM;  // padded sample stride of next level's x
        int g1 = 6 * ((M1 + 127) / 128), g2 = 6 * ((M2 + 127) / 128);

        // conv1 + GELU + mask -> hbuf (padded, bf16); also zeroes hbuf pad row 0
        gemm_conv<0><<<g1, 256, 0, stream>>>(xbuf, Bt1, b1, lens, hbuf, nullptr,
                                             M1, sh_in, a_str, 1, a_str, l);
        // conv2 + mask -> d_out fp32 chunk (+ bf16 next-level x incl. pad rows)
        if (l < 10)
            gemm_conv<1><<<g2, 256, 0, stream>>>(hbuf, Bt2, b2, lens, xbuf, out + y_off,
                                                 M2, sh_out, a_str, 2, x_str, l + 1);
        else
            gemm_conv<2><<<g2, 256, 0, stream>>>(hbuf, Bt2, b2, lens, xbuf, out + y_off,
                                                 M2, sh_out, a_str, 2, x_str, l + 1);
        y_off += (size_t)M2 * C_DIM + (size_t)M2;  // y chunk then mask chunk
    }
}